// Round 5
// baseline (483.865 us; speedup 1.0000x reference)
//
#include <hip/hip_runtime.h>
#include <hip/hip_cooperative_groups.h>
#include <math.h>

namespace cg = cooperative_groups;

#define NN 8192        // n_nodes
#define NE 262144      // edges per adjacency list
#define TOTAL (2*NE)   // 524288
#define CAP 128        // bucket capacity per row (mean 64, sd 8; max ~95)
#define GRID 1024      // 4 blocks/CU at 32 KB LDS (limit is 5) -> coop launch validates
#define NTHREADS (GRID*256)

typedef float f4 __attribute__((ext_vector_type(4)));

struct Pair { int c; float v; };

// Workspace layout (bytes):
//   [0, 32768)              cnt[8192] row cursors
//   [32768, 32772)          ovf_cnt
//   [65536, 65536+8MB)      bucket Pair[8192][128]
//   [65536+8MB, +128KB)     ovf int4[8192]
#define BK_OFF (65536)
#define OV_OFF (65536 + (size_t)NN * CAP * 8)

__device__ __forceinline__ void fill_one(
        int i, float alpha,
        const int* __restrict__ rows_s, const int* __restrict__ cols_s,
        const float* __restrict__ vals_s,
        const int* __restrict__ rows_t, const int* __restrict__ cols_t,
        const float* __restrict__ vals_t,
        int* __restrict__ cnt, Pair* __restrict__ bucket,
        int* __restrict__ ovf_cnt, int4* __restrict__ ovf) {
    int r, c; float v, w;
    if (i < NE) { r = rows_s[i]; c = cols_s[i]; v = vals_s[i]; w = alpha; }
    else { int j = i - NE; r = rows_t[j]; c = cols_t[j]; v = vals_t[j]; w = 1.0f - alpha; }
    float wv = w * v;
    int pos = atomicAdd(&cnt[r], 1);
    if (pos < CAP) {
        Pair p; p.c = c; p.v = wv;
        bucket[r * CAP + pos] = p;
    } else {  // statistically unreachable; kept for correctness
        int k = atomicAdd(ovf_cnt, 1);
        int4 e; e.x = r; e.y = c; e.z = __float_as_int(wv); e.w = 0;
        ovf[k] = e;
    }
}

// Per-row body: LDS accumulate -> row sum from bucket values -> normalized f4 stream-out.
__device__ __forceinline__ void do_row(
        int r, int t, float* row, f4* row4, float* red,
        const int* __restrict__ cnt, const Pair* __restrict__ bucket,
        int no, const int4* __restrict__ ovf, float* __restrict__ out) {
    #pragma unroll
    for (int k = t; k < NN / 4; k += 256) { f4 z = {0.f, 0.f, 0.f, 0.f}; row4[k] = z; }
    int n = cnt[r];
    int nb = n < CAP ? n : CAP;
    __syncthreads();

    float part = 0.0f;
    for (int k = t; k < nb; k += 256) {
        Pair p = bucket[r * CAP + k];
        part += p.v;
        atomicAdd(&row[p.c], p.v);
    }
    if (no > 0) {                      // cold path
        for (int k = t; k < no; k += 256) {
            int4 e = ovf[k];
            if (e.x == r) {
                float v = __int_as_float(e.z);
                part += v;
                atomicAdd(&row[e.y], v);
            }
        }
    }
    #pragma unroll
    for (int o = 32; o > 0; o >>= 1) part += __shfl_down(part, o, 64);
    if ((t & 63) == 0) red[t >> 6] = part;
    __syncthreads();                   // fences LDS atomics + red[] writes
    float total = red[0] + red[1] + red[2] + red[3];
    float inv = (total == 0.0f) ? 1.0f : 1.0f / total;

    f4* out4 = (f4*)(out + (size_t)r * NN);
    #pragma unroll
    for (int k = t; k < NN / 4; k += 256) {
        f4 x = row4[k];
        x *= inv;
        __builtin_nontemporal_store(x, &out4[k]);
    }
}

// Fused: zero cursors -> grid.sync -> bucket fill -> grid.sync -> rows.
__global__ __launch_bounds__(256) void fused_kernel(
        const int* __restrict__ rows_s, const int* __restrict__ cols_s,
        const float* __restrict__ vals_s,
        const int* __restrict__ rows_t, const int* __restrict__ cols_t,
        const float* __restrict__ vals_t,
        const float* __restrict__ gamma,
        int* __restrict__ cnt, Pair* __restrict__ bucket,
        int* __restrict__ ovf_cnt, int4* __restrict__ ovf,
        float* __restrict__ out) {
    cg::grid_group grid = cg::this_grid();
    int tid = blockIdx.x * 256 + threadIdx.x;

    if (tid < NN) cnt[tid] = 0;
    if (tid == 0) *ovf_cnt = 0;
    grid.sync();

    float alpha = 1.0f / (1.0f + expf(-gamma[0]));
    #pragma unroll
    for (int base = 0; base < TOTAL; base += NTHREADS)   // 2 iterations, uniform s/t split
        fill_one(base + tid, alpha, rows_s, cols_s, vals_s, rows_t, cols_t, vals_t,
                 cnt, bucket, ovf_cnt, ovf);
    grid.sync();

    __shared__ float row[NN];          // 32 KB
    __shared__ float red[4];
    f4* row4 = (f4*)row;
    int t = threadIdx.x;
    int no = *ovf_cnt;
    for (int r = blockIdx.x; r < NN; r += GRID) {        // 8 rows/block, no tail
        do_row(r, t, row, row4, red, cnt, bucket, no, ovf, out);
        __syncthreads();               // row[] reuse barrier
    }
}

// ---- Non-cooperative fallback (3-dispatch pipeline, round-4 design) ----
__global__ __launch_bounds__(256) void fill_kernel(
        const int* __restrict__ rows_s, const int* __restrict__ cols_s,
        const float* __restrict__ vals_s,
        const int* __restrict__ rows_t, const int* __restrict__ cols_t,
        const float* __restrict__ vals_t,
        const float* __restrict__ gamma,
        int* __restrict__ cnt, Pair* __restrict__ bucket,
        int* __restrict__ ovf_cnt, int4* __restrict__ ovf) {
    int i = blockIdx.x * blockDim.x + threadIdx.x;
    float alpha = 1.0f / (1.0f + expf(-gamma[0]));
    fill_one(i, alpha, rows_s, cols_s, vals_s, rows_t, cols_t, vals_t,
             cnt, bucket, ovf_cnt, ovf);
}

__global__ __launch_bounds__(256) void row_kernel(
        const int* __restrict__ cnt, const Pair* __restrict__ bucket,
        const int* __restrict__ ovf_cnt, const int4* __restrict__ ovf,
        float* __restrict__ out) {
    __shared__ float row[NN];
    __shared__ float red[4];
    f4* row4 = (f4*)row;
    do_row(blockIdx.x, threadIdx.x, row, row4, red, cnt, bucket, *ovf_cnt, ovf, out);
}

extern "C" void kernel_launch(void* const* d_in, const int* in_sizes, int n_in,
                              void* d_out, int out_size, void* d_ws, size_t ws_size,
                              hipStream_t stream) {
    const int*   rows_s = (const int*)  d_in[0];
    const int*   cols_s = (const int*)  d_in[1];
    const float* vals_s = (const float*)d_in[2];
    const int*   rows_t = (const int*)  d_in[3];
    const int*   cols_t = (const int*)  d_in[4];
    const float* vals_t = (const float*)d_in[5];
    const float* gamma  = (const float*)d_in[6];

    float* out     = (float*)d_out;
    char*  ws      = (char*)d_ws;
    int*   cnt     = (int*)ws;                    // [NN]
    int*   ovf_cnt = (int*)(ws + 32768);          // [1]
    Pair*  bucket  = (Pair*)(ws + BK_OFF);        // [NN*CAP]
    int4*  ovf     = (int4*)(ws + OV_OFF);        // [8192]

    void* args[] = { (void*)&rows_s, (void*)&cols_s, (void*)&vals_s,
                     (void*)&rows_t, (void*)&cols_t, (void*)&vals_t,
                     (void*)&gamma,  (void*)&cnt,    (void*)&bucket,
                     (void*)&ovf_cnt,(void*)&ovf,    (void*)&out };
    hipError_t err = hipLaunchCooperativeKernel((const void*)fused_kernel,
                                                dim3(GRID), dim3(256),
                                                args, 0, stream);
    if (err != hipSuccess) {
        // Fallback: 3-dispatch pipeline.
        (void)hipMemsetAsync(ws, 0, 32772, stream);
        fill_kernel<<<TOTAL / 256, 256, 0, stream>>>(rows_s, cols_s, vals_s,
                                                     rows_t, cols_t, vals_t,
                                                     gamma, cnt, bucket, ovf_cnt, ovf);
        row_kernel<<<NN, 256, 0, stream>>>(cnt, bucket, ovf_cnt, ovf, out);
    }
}

// Round 6
// 310.492 us; speedup vs baseline: 1.5584x; 1.5584x over previous
//
#include <hip/hip_runtime.h>
#include <math.h>

#define NN 8192        // n_nodes
#define NE 262144      // edges per adjacency list
#define TOTAL (2*NE)   // 524288
#define CAP 128        // bucket capacity per row (mean 64, sd 8; max ~95)
#define HALF 4096      // columns per half-row block

typedef float f4 __attribute__((ext_vector_type(4)));

struct Pair { int c; float v; };

// Workspace layout (bytes):
//   [0, 32768)              cnt[8192] row cursors
//   [32768, 32772)          ovf_cnt
//   [65536, 65536+8MB)      bucket Pair[8192][128]
//   [65536+8MB, +128KB)     ovf int4[8192]
#define BK_OFF (65536)
#define OV_OFF (65536 + (size_t)NN * CAP * 8)

// Single-pass bucket build: blend weight applied at scatter time.
// i<NE handles list s, else list t — branch is block-uniform (256 | NE).
__global__ __launch_bounds__(256) void fill_kernel(
        const int* __restrict__ rows_s, const int* __restrict__ cols_s,
        const float* __restrict__ vals_s,
        const int* __restrict__ rows_t, const int* __restrict__ cols_t,
        const float* __restrict__ vals_t,
        const float* __restrict__ gamma,
        int* __restrict__ cnt, Pair* __restrict__ bucket,
        int* __restrict__ ovf_cnt, int4* __restrict__ ovf) {
    int i = blockIdx.x * blockDim.x + threadIdx.x;
    float alpha = 1.0f / (1.0f + expf(-gamma[0]));
    int r, c; float v, w;
    if (i < NE) { r = rows_s[i]; c = cols_s[i]; v = vals_s[i]; w = alpha; }
    else { int j = i - NE; r = rows_t[j]; c = cols_t[j]; v = vals_t[j]; w = 1.0f - alpha; }
    float wv = w * v;
    int pos = atomicAdd(&cnt[r], 1);
    if (pos < CAP) {
        Pair p; p.c = c; p.v = wv;
        bucket[r * CAP + pos] = p;
    } else {  // statistically unreachable at these sizes; kept for correctness
        int k = atomicAdd(ovf_cnt, 1);
        int4 e; e.x = r; e.y = c; e.z = __float_as_int(wv); e.w = 0;
        ovf[k] = e;
    }
}

// One block per HALF-row (16 KB LDS -> 8 blocks/CU, 32 waves/CU, zero tail).
// Row sum uses ALL of the row's bucket values (same addend set as the
// reference's dense row sum, reordered); LDS scatter filters to this half's
// column range. Stores drain at kernel end -> fully overlapped across blocks.
__global__ __launch_bounds__(256) void row_kernel(
        const int* __restrict__ cnt, const Pair* __restrict__ bucket,
        const int* __restrict__ ovf_cnt, const int4* __restrict__ ovf,
        float* __restrict__ out) {
    __shared__ float row[HALF];        // 16 KB
    __shared__ float red[4];
    int r    = blockIdx.x >> 1;
    int cbase = (blockIdx.x & 1) * HALF;
    int t = threadIdx.x;

    f4* row4 = (f4*)row;
    #pragma unroll
    for (int k = t; k < HALF / 4; k += 256) { f4 z = {0.f, 0.f, 0.f, 0.f}; row4[k] = z; }
    int n = cnt[r];
    int nb = n < CAP ? n : CAP;
    __syncthreads();

    float part = 0.0f;
    for (int k = t; k < nb; k += 256) {
        Pair p = bucket[r * CAP + k];
        part += p.v;                          // full-row sum: no column filter
        int lc = p.c - cbase;
        if ((unsigned)lc < HALF) atomicAdd(&row[lc], p.v);
    }
    int no = *ovf_cnt;
    if (no > 0) {                             // cold path, normally 0 entries
        for (int k = t; k < no; k += 256) {
            int4 e = ovf[k];
            if (e.x == r) {
                float v = __int_as_float(e.z);
                part += v;
                int lc = e.y - cbase;
                if ((unsigned)lc < HALF) atomicAdd(&row[lc], v);
            }
        }
    }

    #pragma unroll
    for (int o = 32; o > 0; o >>= 1) part += __shfl_down(part, o, 64);
    if ((t & 63) == 0) red[t >> 6] = part;
    __syncthreads();                          // fences LDS atomics + red[]
    float total = red[0] + red[1] + red[2] + red[3];
    float inv = (total == 0.0f) ? 1.0f : 1.0f / total;

    f4* out4 = (f4*)(out + (size_t)r * NN + cbase);
    #pragma unroll
    for (int k = t; k < HALF / 4; k += 256) {
        f4 x = row4[k];
        x *= inv;
        __builtin_nontemporal_store(x, &out4[k]);
    }
}

extern "C" void kernel_launch(void* const* d_in, const int* in_sizes, int n_in,
                              void* d_out, int out_size, void* d_ws, size_t ws_size,
                              hipStream_t stream) {
    const int*   rows_s = (const int*)  d_in[0];
    const int*   cols_s = (const int*)  d_in[1];
    const float* vals_s = (const float*)d_in[2];
    const int*   rows_t = (const int*)  d_in[3];
    const int*   cols_t = (const int*)  d_in[4];
    const float* vals_t = (const float*)d_in[5];
    const float* gamma  = (const float*)d_in[6];

    float* out     = (float*)d_out;
    char*  ws      = (char*)d_ws;
    int*   cnt     = (int*)ws;                    // [NN]
    int*   ovf_cnt = (int*)(ws + 32768);          // [1]
    Pair*  bucket  = (Pair*)(ws + BK_OFF);        // [NN*CAP]
    int4*  ovf     = (int4*)(ws + OV_OFF);        // [8192]

    // Zero cursors + overflow counter (ws is poisoned with 0xAA).
    (void)hipMemsetAsync(ws, 0, 32772, stream);

    fill_kernel<<<TOTAL / 256, 256, 0, stream>>>(rows_s, cols_s, vals_s,
                                                 rows_t, cols_t, vals_t,
                                                 gamma, cnt, bucket, ovf_cnt, ovf);
    row_kernel<<<2 * NN, 256, 0, stream>>>(cnt, bucket, ovf_cnt, ovf, out);
}